// Round 4
// baseline (224.793 us; speedup 1.0000x reference)
//
#include <hip/hip_runtime.h>

// GAT: B=256, N=64, K=12, D=128
// Algebraic reduction: q/k projections fold into effective vectors
//   wq_eff = Wq @ wa_q, wk_eff = Wk @ wa_k  (only q.wa_q / k.wa_k are used)
// and the V projection commutes with the attention average:
//   out = (sum_j attn_j nh_j) @ Wv + bv * (sum_j attn_j)
// FLOPs drop 14.5G -> 0.65G; bound by streaming the 118 MB of inputs.
//
// R3 failed POST-TIMING only (first validation passed): the prep->fused
// d_ws handoff is the lone cross-launch-visible state and d_ws is poisoned
// 0xAA around every timed launch -> race class "global intermediate state".
// R4: ONE kernel, ZERO d_ws. Each block recomputes wq_eff/wk_eff/cst into
// LDS (64KB L2-resident row-dots, ~8us aggregate L2 time, overlapped).
// All cross-phase data lives in LDS; blocks are fully self-contained.

#define B_  256
#define N_  64
#define K_  12
#define D_  128
#define BN  (B_ * N_)          // 16384 (b,n) pairs
#define ROWS 8                 // pairs per block
#define NBLK (BN / ROWS)       // 2048 blocks
#define HB_STRIDE 132

__global__ void __launch_bounds__(256)
fused_kernel(const float* __restrict__ nodes, const float* __restrict__ neigh,
             const float* __restrict__ mask,
             const float* __restrict__ Wq, const float* __restrict__ bq,
             const float* __restrict__ Wk, const float* __restrict__ bk,
             const float* __restrict__ Wv, const float* __restrict__ bv,
             const float* __restrict__ wa_q, const float* __restrict__ wa_k,
             const float* __restrict__ ba_p, float* __restrict__ out) {
    __shared__ float weff[256];              // [0..127] wq_eff | [128..255] wk_eff
    __shared__ float hb[ROWS * HB_STRIDE];   // pooled hidden rows
    __shared__ float scL[ROWS];              // sum of attn weights per row
    __shared__ float cstS;                   // bq.wa_q + bk.wa_k + ba

    const int t    = threadIdx.x;
    const int wave = t >> 6;
    const int l    = t & 63;

    // ---- Phase 0: per-block prep (no cross-kernel state) ----
    {
        const float*  wrow = (t < 128) ? (Wq + (size_t)t * D_) : (Wk + (size_t)(t - 128) * D_);
        const float*  wa   = (t < 128) ? wa_q : wa_k;
        const float4* wr4  = (const float4*)wrow;
        const float4* wa4  = (const float4*)wa;
        float acc = 0.0f;
        #pragma unroll
        for (int k = 0; k < 32; ++k) {
            float4 a = wr4[k], b = wa4[k];
            acc += a.x * b.x + a.y * b.y + a.z * b.z + a.w * b.w;
        }
        weff[t] = acc;
    }
    if (wave == 0) {
        float2 q2  = ((const float2*)bq)[l];
        float2 k2  = ((const float2*)bk)[l];
        float2 aq2 = ((const float2*)wa_q)[l];
        float2 ak2 = ((const float2*)wa_k)[l];
        float c = q2.x * aq2.x + q2.y * aq2.y + k2.x * ak2.x + k2.y * ak2.y;
        #pragma unroll
        for (int m = 1; m < 64; m <<= 1) c += __shfl_xor(c, m, 64);
        if (l == 0) cstS = c + ba_p[0];
    }
    __syncthreads();

    const float cst = cstS;
    const float2 wqe = ((const float2*)weff)[l];          // wq_eff[2l..2l+1]
    const float2 wke = ((const float2*)(weff + 128))[l];  // wk_eff[2l..2l+1]

    // ---- Phase A: attention for this wave's 2 pairs (unrolled for MLP) ----
    #pragma unroll
    for (int p = 0; p < 2; ++p) {
        const int lrow = wave * 2 + p;                 // 0..7 local row
        const int idx  = blockIdx.x * ROWS + lrow;     // (b,n) flat index

        const float2* np = (const float2*)(nodes + (size_t)idx * D_);
        const float2* gp = (const float2*)(neigh + (size_t)idx * K_ * D_);

        // x[0] = node itself (prepended slot), x[1..12] = neighbors
        float2 x[K_ + 1];
        x[0] = np[l];
        #pragma unroll
        for (int j = 0; j < K_; ++j) x[j + 1] = gp[j * 64 + l];

        float mval = (l < K_) ? mask[(size_t)idx * K_ + l] : 0.0f;

        // per-lane partial dot products
        float pq = x[0].x * wqe.x + x[0].y * wqe.y;
        float pk[K_ + 1];
        #pragma unroll
        for (int j = 0; j <= K_; ++j) pk[j] = x[j].x * wke.x + x[j].y * wke.y;

        // 14 wave butterfly reductions; all lanes end with full sums
        #pragma unroll
        for (int m = 1; m < 64; m <<= 1) {
            pq += __shfl_xor(pq, m, 64);
            #pragma unroll
            for (int j = 0; j <= K_; ++j) pk[j] += __shfl_xor(pk[j], m, 64);
        }

        const float base = pq + cst;
        float e[K_ + 1];
        float S = 0.0f;
        #pragma unroll
        for (int j = 0; j <= K_; ++j) {
            float s = base + pk[j];
            s = (s >= 0.0f) ? s : 0.2f * s;           // LeakyReLU(0.2)
            float mj = (j == 0) ? 1.0f : __shfl(mval, j - 1, 64);
            e[j] = __expf(s) * mj;                    // masked exp
            S += e[j];
        }
        const float inv = 1.0f / (S + 1e-16f);

        float h0 = 0.0f, h1 = 0.0f;
        #pragma unroll
        for (int j = 0; j <= K_; ++j) {
            float w = e[j] * inv;
            h0 += w * x[j].x;
            h1 += w * x[j].y;
        }

        *(float2*)(hb + lrow * HB_STRIDE + 2 * l) = make_float2(h0, h1);
        if (l == 0) scL[lrow] = S * inv;              // sum of attn weights
    }
    __syncthreads();

    // ---- Phase B: out[8x128] = hb @ Wv + bv * scale ----
    const int row  = t >> 5;                      // 0..7
    const int cg   = t & 31;                      // cols cg*4..+3
    const int row0 = blockIdx.x * ROWS;
    const float4* wv4 = (const float4*)Wv;        // [k][32] of float4

    float4 acc = make_float4(0.f, 0.f, 0.f, 0.f);
    #pragma unroll 8
    for (int k = 0; k < D_; ++k) {
        float4 b = wv4[k * 32 + cg];
        float  a = hb[row * HB_STRIDE + k];
        acc.x += a * b.x;
        acc.y += a * b.y;
        acc.z += a * b.z;
        acc.w += a * b.w;
    }

    float4 bvv = ((const float4*)bv)[cg];
    float  s   = scL[row];
    float4 o;
    o.x = acc.x + bvv.x * s;
    o.y = acc.y + bvv.y * s;
    o.z = acc.z + bvv.z * s;
    o.w = acc.w + bvv.w * s;
    *(float4*)(out + (size_t)(row0 + row) * D_ + cg * 4) = o;
}

// ---------------------------------------------------------------------------
extern "C" void kernel_launch(void* const* d_in, const int* in_sizes, int n_in,
                              void* d_out, int out_size, void* d_ws, size_t ws_size,
                              hipStream_t stream) {
    const float* nodes = (const float*)d_in[0];
    const float* neigh = (const float*)d_in[1];
    const float* mask  = (const float*)d_in[2];
    const float* Wq    = (const float*)d_in[3];
    const float* bq    = (const float*)d_in[4];
    const float* Wk    = (const float*)d_in[5];
    const float* bk    = (const float*)d_in[6];
    const float* Wv    = (const float*)d_in[7];
    const float* bv    = (const float*)d_in[8];
    const float* wa_q  = (const float*)d_in[9];
    const float* wa_k  = (const float*)d_in[10];
    const float* ba    = (const float*)d_in[11];
    float* out = (float*)d_out;

    fused_kernel<<<NBLK, 256, 0, stream>>>(nodes, neigh, mask, Wq, bq, Wk, bk,
                                           Wv, bv, wa_q, wa_k, ba, out);
}

// Round 5
// 224.563 us; speedup vs baseline: 1.0010x; 1.0010x over previous
//
#include <hip/hip_runtime.h>

// GAT: B=256, N=64, K=12, D=128
// Folding: wq_eff = Wq@wa_q, wk_eff = Wk@wa_k (only score projections used);
// out = (sum_j attn_j nh_j) @ Wv + bv * (sum_j attn_j).
// Self-contained blocks, zero d_ws (R3 post-timing failure = ws handoff race).
//
// R5 vs R4 (98.5us):
//  - Phase 0 coalesced: row-per-wave-iteration (512B contiguous/instr) instead
//    of row-per-thread (64 lines/instr TA storm, ~25-35us of the R4 time).
//  - ROWS 8->16 (1024 blocks): halves per-block prep redundancy.
//  - Phase A: explicit 2-pair software pipeline (xa/xb reg buffers) so ~13KB
//    of loads stay in flight per wave (R4's VGPR=44 proved serial pairs).
//  - Phase B: 2 rows x 4 cols per thread -> halves Wv L1 traffic per row.

#define B_  256
#define N_  64
#define K_  12
#define D_  128
#define BN  (B_ * N_)          // 16384 (b,n) pairs
#define ROWS 16                // pairs per block
#define NBLK (BN / ROWS)       // 1024 blocks
#define HB_STRIDE 132

__global__ void __launch_bounds__(256)
fused_kernel(const float* __restrict__ nodes, const float* __restrict__ neigh,
             const float* __restrict__ mask,
             const float* __restrict__ Wq, const float* __restrict__ bq,
             const float* __restrict__ Wk, const float* __restrict__ bk,
             const float* __restrict__ Wv, const float* __restrict__ bv,
             const float* __restrict__ wa_q, const float* __restrict__ wa_k,
             const float* __restrict__ ba_p, float* __restrict__ out) {
    __shared__ float weff[256];              // [0..127] wq_eff | [128..255] wk_eff
    __shared__ float hb[ROWS * HB_STRIDE];   // pooled hidden rows
    __shared__ float scL[ROWS];              // sum of attn weights per row
    __shared__ float cstS;                   // bq.wa_q + bk.wa_k + ba

    const int t    = threadIdx.x;
    const int wave = t >> 6;
    const int l    = t & 63;

    // ---- Phase 0: folded vectors, COALESCED. Wave w owns 64 rows:
    // waves 0,1 -> Wq rows 0-63 / 64-127; waves 2,3 -> Wk rows 0-63 / 64-127.
    // Per row: lane l loads W[r][2l..2l+1] (512B contiguous), butterfly-sum.
    {
        const bool isQ  = (wave < 2);
        const float* Wm = isQ ? Wq : Wk;
        const float* wa = isQ ? wa_q : wa_k;
        const int base  = (wave & 1) * 64;
        const int obase = isQ ? 0 : 128;
        float2 wav = ((const float2*)wa)[l];
        #pragma unroll 4
        for (int i = 0; i < 64; ++i) {
            float2 w2 = ((const float2*)(Wm + (size_t)(base + i) * D_))[l];
            float p = w2.x * wav.x + w2.y * wav.y;
            #pragma unroll
            for (int m = 1; m < 64; m <<= 1) p += __shfl_xor(p, m, 64);
            if (l == 0) weff[obase + base + i] = p;
        }
    }
    if (wave == 0) {
        float2 q2  = ((const float2*)bq)[l];
        float2 k2  = ((const float2*)bk)[l];
        float2 aq2 = ((const float2*)wa_q)[l];
        float2 ak2 = ((const float2*)wa_k)[l];
        float c = q2.x * aq2.x + q2.y * aq2.y + k2.x * ak2.x + k2.y * ak2.y;
        #pragma unroll
        for (int m = 1; m < 64; m <<= 1) c += __shfl_xor(c, m, 64);
        if (l == 0) cstS = c + ba_p[0];
    }
    __syncthreads();

    const float cst  = cstS;
    const float2 wqe = ((const float2*)weff)[l];          // wq_eff[2l..2l+1]
    const float2 wke = ((const float2*)(weff + 128))[l];  // wk_eff[2l..2l+1]

    // ---- Phase A: 4 pairs per wave, 2-deep software pipeline ----
    float2 xa[K_ + 1], xb[K_ + 1];
    float ma, mb;

#define LOADP(X, M, p) do {                                                   \
        const int idx_ = blockIdx.x * ROWS + wave * 4 + (p);                  \
        const float2* np_ = (const float2*)(nodes + (size_t)idx_ * D_);       \
        const float2* gp_ = (const float2*)(neigh + (size_t)idx_ * (K_*D_)); \
        X[0] = np_[l];                                                        \
        _Pragma("unroll")                                                     \
        for (int j = 0; j < K_; ++j) X[j + 1] = gp_[j * 64 + l];              \
        M = (l < K_) ? mask[(size_t)idx_ * K_ + l] : 0.0f;                    \
    } while (0)

#define PROCP(X, M, p) do {                                                   \
        const int lrow_ = wave * 4 + (p);                                     \
        float pq = X[0].x * wqe.x + X[0].y * wqe.y;                           \
        float pk[K_ + 1];                                                     \
        _Pragma("unroll")                                                     \
        for (int j = 0; j <= K_; ++j)                                         \
            pk[j] = X[j].x * wke.x + X[j].y * wke.y;                          \
        _Pragma("unroll")                                                     \
        for (int m_ = 1; m_ < 64; m_ <<= 1) {                                 \
            pq += __shfl_xor(pq, m_, 64);                                     \
            _Pragma("unroll")                                                 \
            for (int j = 0; j <= K_; ++j) pk[j] += __shfl_xor(pk[j], m_, 64); \
        }                                                                     \
        const float base_ = pq + cst;                                         \
        float e[K_ + 1];                                                      \
        float S = 0.0f;                                                       \
        _Pragma("unroll")                                                     \
        for (int j = 0; j <= K_; ++j) {                                       \
            float s_ = base_ + pk[j];                                         \
            s_ = (s_ >= 0.0f) ? s_ : 0.2f * s_;                               \
            float mj = (j == 0) ? 1.0f : __shfl(M, j - 1, 64);                \
            e[j] = __expf(s_) * mj;                                           \
            S += e[j];                                                        \
        }                                                                     \
        const float inv_ = 1.0f / (S + 1e-16f);                               \
        float h0 = 0.0f, h1 = 0.0f;                                           \
        _Pragma("unroll")                                                     \
        for (int j = 0; j <= K_; ++j) {                                       \
            float w_ = e[j] * inv_;                                           \
            h0 += w_ * X[j].x;                                                \
            h1 += w_ * X[j].y;                                                \
        }                                                                     \
        *(float2*)(hb + lrow_ * HB_STRIDE + 2 * l) = make_float2(h0, h1);     \
        if (l == 0) scL[lrow_] = S * inv_;                                    \
    } while (0)

    LOADP(xa, ma, 0);
    LOADP(xb, mb, 1);
    PROCP(xa, ma, 0);
    LOADP(xa, ma, 2);
    PROCP(xb, mb, 1);
    LOADP(xb, mb, 3);
    PROCP(xa, ma, 2);
    PROCP(xb, mb, 3);

#undef LOADP
#undef PROCP

    __syncthreads();

    // ---- Phase B: out[16x128] = hb @ Wv + bv * scale; 2 rows x 4 cols/thread
    const int rg   = t >> 5;                      // 0..7 -> rows rg, rg+8
    const int cg   = t & 31;                      // cols cg*4..+3
    const int row0 = blockIdx.x * ROWS;
    const float4* wv4 = (const float4*)Wv;        // [k][32] of float4

    float4 acc0 = make_float4(0.f, 0.f, 0.f, 0.f);
    float4 acc1 = make_float4(0.f, 0.f, 0.f, 0.f);
    #pragma unroll 8
    for (int k = 0; k < D_; ++k) {
        float4 b  = wv4[k * 32 + cg];
        float  a0 = hb[rg * HB_STRIDE + k];
        float  a1 = hb[(rg + 8) * HB_STRIDE + k];
        acc0.x += a0 * b.x;  acc0.y += a0 * b.y;
        acc0.z += a0 * b.z;  acc0.w += a0 * b.w;
        acc1.x += a1 * b.x;  acc1.y += a1 * b.y;
        acc1.z += a1 * b.z;  acc1.w += a1 * b.w;
    }

    float4 bvv = ((const float4*)bv)[cg];
    {
        float s = scL[rg];
        float4 o;
        o.x = acc0.x + bvv.x * s;  o.y = acc0.y + bvv.y * s;
        o.z = acc0.z + bvv.z * s;  o.w = acc0.w + bvv.w * s;
        *(float4*)(out + (size_t)(row0 + rg) * D_ + cg * 4) = o;
    }
    {
        float s = scL[rg + 8];
        float4 o;
        o.x = acc1.x + bvv.x * s;  o.y = acc1.y + bvv.y * s;
        o.z = acc1.z + bvv.z * s;  o.w = acc1.w + bvv.w * s;
        *(float4*)(out + (size_t)(row0 + rg + 8) * D_ + cg * 4) = o;
    }
}

// ---------------------------------------------------------------------------
extern "C" void kernel_launch(void* const* d_in, const int* in_sizes, int n_in,
                              void* d_out, int out_size, void* d_ws, size_t ws_size,
                              hipStream_t stream) {
    const float* nodes = (const float*)d_in[0];
    const float* neigh = (const float*)d_in[1];
    const float* mask  = (const float*)d_in[2];
    const float* Wq    = (const float*)d_in[3];
    const float* bq    = (const float*)d_in[4];
    const float* Wk    = (const float*)d_in[5];
    const float* bk    = (const float*)d_in[6];
    const float* Wv    = (const float*)d_in[7];
    const float* bv    = (const float*)d_in[8];
    const float* wa_q  = (const float*)d_in[9];
    const float* wa_k  = (const float*)d_in[10];
    const float* ba    = (const float*)d_in[11];
    float* out = (float*)d_out;

    fused_kernel<<<NBLK, 256, 0, stream>>>(nodes, neigh, mask, Wq, bq, Wk, bk,
                                           Wv, bv, wa_q, wa_k, ba, out);
}

// Round 6
// 203.489 us; speedup vs baseline: 1.1047x; 1.1036x over previous
//
#include <hip/hip_runtime.h>

// GAT: B=256, N=64, K=12, D=128
// Folding: wq_eff = Wq@wa_q, wk_eff = Wk@wa_k (only score projections used);
// out = (sum_j attn_j nh_j) @ Wv + bv * (sum_j attn_j).
// Self-contained blocks, zero d_ws (R3 post-timing failure = ws handoff race).
//
// R6 theory: R4/R5's 98us is LDS-pipe serialization (~1000 shuffle/ds ops per
// wave: 6-deep dependent butterfly chains). Restructure to minimize cross-lane:
//  - Phase A: 32 lanes/pair (2 pairs per wave-instr), query partial folded into
//    slot partials BEFORE reduce -> 5 stages x 13 values = 65 shuffle instrs
//    per 2 pairs (vs 192). Mask via one __ballot (vs 12 shfl/pair).
//  - Phase 0: 16 lanes/row, 8 dims in-lane -> 4-stage butterfly, 64 shfl/wave
//    (vs 384), loads stay coalesced (32 lines / 2KB region per instr).
//  - Phase B: ds_read_b128 + unroll-4 -> 64 LDS reads/wave (vs 256 b32).

#define B_  256
#define N_  64
#define K_  12
#define D_  128
#define BN  (B_ * N_)          // 16384 (b,n) pairs
#define ROWS 16                // pairs per block
#define NBLK (BN / ROWS)       // 1024 blocks
#define HB_STRIDE 132          // floats; 528B row stride (16B-aligned for float4)

__global__ void __launch_bounds__(256, 4)
fused_kernel(const float* __restrict__ nodes, const float* __restrict__ neigh,
             const float* __restrict__ mask,
             const float* __restrict__ Wq, const float* __restrict__ bq,
             const float* __restrict__ Wk, const float* __restrict__ bk,
             const float* __restrict__ Wv, const float* __restrict__ bv,
             const float* __restrict__ wa_q, const float* __restrict__ wa_k,
             const float* __restrict__ ba_p, float* __restrict__ out) {
    __shared__ float weff[256];              // [0..127] wq_eff | [128..255] wk_eff
    __shared__ float hb[ROWS * HB_STRIDE];   // pooled hidden rows
    __shared__ float scL[ROWS];              // sum of attn weights per row
    __shared__ float cstS;                   // bq.wa_q + bk.wa_k + ba

    const int t    = threadIdx.x;
    const int wave = t >> 6;
    const int l    = t & 63;

    // ---- Phase 0: weff, 16 lanes per row (8 dims in-lane, 4-stage reduce) ----
    {
        const bool  isQ  = (wave < 2);
        const float* Wm  = isQ ? Wq : Wk;
        const float* wav = isQ ? wa_q : wa_k;
        const int sub    = l & 15;           // lane within row-group
        const int rquad  = l >> 4;           // 4 rows per iteration
        const int rbase  = (wave & 1) * 64;
        const int obase  = isQ ? 0 : 128;
        float4 wv0 = ((const float4*)wav)[sub * 2];
        float4 wv1 = ((const float4*)wav)[sub * 2 + 1];
        #pragma unroll 4
        for (int i = 0; i < 16; ++i) {
            int r = rbase + i * 4 + rquad;
            const float4* wr = (const float4*)(Wm + (size_t)r * D_);
            float4 a0 = wr[sub * 2], a1 = wr[sub * 2 + 1];
            float p = a0.x * wv0.x + a0.y * wv0.y + a0.z * wv0.z + a0.w * wv0.w
                    + a1.x * wv1.x + a1.y * wv1.y + a1.z * wv1.z + a1.w * wv1.w;
            p += __shfl_xor(p, 1, 64);
            p += __shfl_xor(p, 2, 64);
            p += __shfl_xor(p, 4, 64);
            p += __shfl_xor(p, 8, 64);
            if (sub == 0) weff[obase + r] = p;
        }
    }
    if (wave == 0) {
        float2 q2  = ((const float2*)bq)[l];
        float2 k2  = ((const float2*)bk)[l];
        float2 aq2 = ((const float2*)wa_q)[l];
        float2 ak2 = ((const float2*)wa_k)[l];
        float c = q2.x * aq2.x + q2.y * aq2.y + k2.x * ak2.x + k2.y * ak2.y;
        #pragma unroll
        for (int m = 1; m < 64; m <<= 1) c += __shfl_xor(c, m, 64);
        if (l == 0) cstS = c + ba_p[0];
    }
    __syncthreads();

    const float cst = cstS;
    const int h = l >> 5;                    // half: which pair of the duo
    const int s = l & 31;                    // lane within pair; dims s*4..s*4+3
    const float4 wqe = ((const float4*)weff)[s];
    const float4 wke = ((const float4*)(weff + 128))[s];

    // ---- Phase A: 2 iterations x 2 pairs (halves); 65 shuffles per iter ----
    #pragma unroll
    for (int i = 0; i < 2; ++i) {
        const int lrow = wave * 4 + i * 2 + h;         // 0..15 local row
        const int idx  = blockIdx.x * ROWS + lrow;     // (b,n) flat index

        const float4* np = (const float4*)(nodes + (size_t)idx * D_);
        const float4* gp = (const float4*)(neigh + (size_t)idx * (K_ * D_));

        float4 x[K_ + 1];
        x[0] = np[s];
        #pragma unroll
        for (int j = 0; j < K_; ++j) x[j + 1] = gp[j * 32 + s];

        float mval = (s < K_) ? mask[(size_t)idx * K_ + s] : 0.0f;
        unsigned long long mbits = __ballot(mval > 0.5f);

        // fold query partial into each slot partial BEFORE the reduce
        float pq = x[0].x * wqe.x + x[0].y * wqe.y + x[0].z * wqe.z + x[0].w * wqe.w;
        float tj[K_ + 1];
        #pragma unroll
        for (int j = 0; j <= K_; ++j)
            tj[j] = pq + x[j].x * wke.x + x[j].y * wke.y
                       + x[j].z * wke.z + x[j].w * wke.w;

        // 5-stage butterfly within 32-lane halves (xor<32 never crosses)
        #pragma unroll
        for (int m = 1; m < 32; m <<= 1) {
            #pragma unroll
            for (int j = 0; j <= K_; ++j) tj[j] += __shfl_xor(tj[j], m, 64);
        }

        float e[K_ + 1];
        float S = 0.0f;
        #pragma unroll
        for (int j = 0; j <= K_; ++j) {
            float sc = tj[j] + cst;
            sc = (sc >= 0.0f) ? sc : 0.2f * sc;        // LeakyReLU(0.2)
            float mj = (j == 0) ? 1.0f
                     : (((mbits >> (h * 32 + j - 1)) & 1ull) ? 1.0f : 0.0f);
            e[j] = __expf(sc) * mj;                    // masked exp
            S += e[j];
        }
        const float inv = 1.0f / (S + 1e-16f);

        float4 hacc = make_float4(0.f, 0.f, 0.f, 0.f);
        #pragma unroll
        for (int j = 0; j <= K_; ++j) {
            float w = e[j] * inv;
            hacc.x += w * x[j].x;  hacc.y += w * x[j].y;
            hacc.z += w * x[j].z;  hacc.w += w * x[j].w;
        }
        *(float4*)(hb + lrow * HB_STRIDE + s * 4) = hacc;
        if (s == 0) scL[lrow] = S * inv;
    }
    __syncthreads();

    // ---- Phase B: out[16x128] = hb @ Wv + bv*scale; b128 LDS reads ----
    const int rg   = t >> 5;                      // rows rg, rg+8
    const int cg   = t & 31;                      // cols cg*4..+3
    const int row0 = blockIdx.x * ROWS;
    const float4* wv4 = (const float4*)Wv;

    float4 acc0 = make_float4(0.f, 0.f, 0.f, 0.f);
    float4 acc1 = make_float4(0.f, 0.f, 0.f, 0.f);
    #pragma unroll 4
    for (int k4 = 0; k4 < 32; ++k4) {
        float4 a0 = *(const float4*)(hb + rg * HB_STRIDE + k4 * 4);
        float4 a1 = *(const float4*)(hb + (rg + 8) * HB_STRIDE + k4 * 4);
        #pragma unroll
        for (int kk = 0; kk < 4; ++kk) {
            float4 b  = wv4[(k4 * 4 + kk) * 32 + cg];
            float av0 = (&a0.x)[kk];
            float av1 = (&a1.x)[kk];
            acc0.x += av0 * b.x;  acc0.y += av0 * b.y;
            acc0.z += av0 * b.z;  acc0.w += av0 * b.w;
            acc1.x += av1 * b.x;  acc1.y += av1 * b.y;
            acc1.z += av1 * b.z;  acc1.w += av1 * b.w;
        }
    }

    float4 bvv = ((const float4*)bv)[cg];
    {
        float sc = scL[rg];
        float4 o;
        o.x = acc0.x + bvv.x * sc;  o.y = acc0.y + bvv.y * sc;
        o.z = acc0.z + bvv.z * sc;  o.w = acc0.w + bvv.w * sc;
        *(float4*)(out + (size_t)(row0 + rg) * D_ + cg * 4) = o;
    }
    {
        float sc = scL[rg + 8];
        float4 o;
        o.x = acc1.x + bvv.x * sc;  o.y = acc1.y + bvv.y * sc;
        o.z = acc1.z + bvv.z * sc;  o.w = acc1.w + bvv.w * sc;
        *(float4*)(out + (size_t)(row0 + rg + 8) * D_ + cg * 4) = o;
    }
}

// ---------------------------------------------------------------------------
extern "C" void kernel_launch(void* const* d_in, const int* in_sizes, int n_in,
                              void* d_out, int out_size, void* d_ws, size_t ws_size,
                              hipStream_t stream) {
    const float* nodes = (const float*)d_in[0];
    const float* neigh = (const float*)d_in[1];
    const float* mask  = (const float*)d_in[2];
    const float* Wq    = (const float*)d_in[3];
    const float* bq    = (const float*)d_in[4];
    const float* Wk    = (const float*)d_in[5];
    const float* bk    = (const float*)d_in[6];
    const float* Wv    = (const float*)d_in[7];
    const float* bv    = (const float*)d_in[8];
    const float* wa_q  = (const float*)d_in[9];
    const float* wa_k  = (const float*)d_in[10];
    const float* ba    = (const float*)d_in[11];
    float* out = (float*)d_out;

    fused_kernel<<<NBLK, 256, 0, stream>>>(nodes, neigh, mask, Wq, bq, Wk, bk,
                                           Wv, bv, wa_q, wa_k, ba, out);
}